// Round 11
// baseline (103.052 us; speedup 1.0000x reference)
//
#include <hip/hip_runtime.h>
#include <hip/hip_bf16.h>

#define S_LEN 2048
#define NHEADS 32
#define NKV 8
#define HD 128
#define QK_SCALE 0.08838834764831845f           // 1/sqrt(128)
#define LOG2E 1.4426950408889634f
#define QK_SCALE2 (QK_SCALE * LOG2E)            // folded into Q (log2 domain)
#define DTHR 11.5416f                           // defer-max threshold (8 nats in log2)

#define BQ 128                // q rows per block (8 waves x 16)
#define BK 32                 // kv rows per tile
#define NQT (S_LEN / BQ)      // 16 q tiles
#define QSTR (NHEADS * HD)    // 4096
#define KSTR (NKV * HD)       // 1024

#define K_STRIDE 136          // LDS row stride (shorts)
#define VT_STRIDE 40
#define P_STRIDE 40

typedef __attribute__((ext_vector_type(8))) short bf16x8;
typedef __attribute__((ext_vector_type(4))) float f32x4;
typedef __attribute__((ext_vector_type(4))) unsigned u32x4;
typedef __attribute__((ext_vector_type(2))) unsigned u32x2;

__device__ inline unsigned cvt_pk_bf16(float lo, float hi) {
    unsigned r;
    asm("v_cvt_pk_bf16_f32 %0, %1, %2" : "=v"(r) : "v"(lo), "v"(hi));
    return r;
}
__device__ inline bf16x8 as_bf16x8(u32x4 v) {
    union { u32x4 u; bf16x8 b; } c; c.u = v; return c.b;
}

__global__ __launch_bounds__(512) void attn_fwd(
    const float* __restrict__ Q, const float* __restrict__ K,
    const float* __restrict__ V, const float* __restrict__ SL,
    float* __restrict__ O)
{
    const int bx   = blockIdx.x;
    const int h    = bx & (NHEADS - 1);
    const int qt   = (NQT - 1) - (bx >> 5);     // heavy q-tiles dispatch first
    const int kvh  = h >> 2;
    const float slope  = SL[h];
    const float slope2 = slope * LOG2E;

    const int tid  = threadIdx.x;
    const int w    = tid >> 6;                  // wave 0..7
    const int lane = tid & 63;
    const int l16  = lane & 15;
    const int lq   = lane >> 4;

    __shared__ short Ks[2][BK * K_STRIDE];     // double-buffered K [k][d]
    __shared__ short VTs[2][HD * VT_STRIDE];   // double-buffered V^T [d][k]
    __shared__ short Ps[8][16 * P_STRIDE];     // per-wave P [q][k]

    const int qrow0 = qt * BQ + w * 16;
    const int q     = qrow0 + l16;             // this lane's q row (swapped layout)

    // ---- Q fragment (B-operand; scale*log2e folded in) ----
    bf16x8 qf[4];
    {
        const float* qp = Q + (size_t)q * QSTR + h * HD + lq * 8;
        #pragma unroll
        for (int d0 = 0; d0 < 4; ++d0) {
            f32x4 a = *(const f32x4*)(qp + d0 * 32);
            f32x4 b = *(const f32x4*)(qp + d0 * 32 + 4);
            u32x4 t;
            t[0] = cvt_pk_bf16(a[0] * QK_SCALE2, a[1] * QK_SCALE2);
            t[1] = cvt_pk_bf16(a[2] * QK_SCALE2, a[3] * QK_SCALE2);
            t[2] = cvt_pk_bf16(b[0] * QK_SCALE2, b[1] * QK_SCALE2);
            t[3] = cvt_pk_bf16(b[2] * QK_SCALE2, b[3] * QK_SCALE2);
            qf[d0] = as_bf16x8(t);
        }
    }

    // acc holds O^T: acc[t][i] = O[q][t*16 + 4*lq + i]
    f32x4 acc[8];
    #pragma unroll
    for (int t = 0; t < 8; ++t) acc[t] = (f32x4){0.f, 0.f, 0.f, 0.f};
    float m_ = -1e30f, l_ = 0.f;               // per-lane scalars (one q per lane)

    const int kv_end = qt * BQ + BQ;
    int kb_start = 0;
    {   // ALiBi far-tile skip (weight <= e^-33 vs diagonal)
        float th = (float)(qt * BQ) - 31.0f - 45.0f / slope;
        int t = (int)floorf(th);
        kb_start = (t < 0) ? 0 : (((t >> 5) + 1) << 5);
    }

    // ---- staging thread mapping (512 threads: half the work of R10) ----
    const int sr  = tid >> 4, scc = tid & 15;   // K: row sr (0..31), chunk scc
    const int vd  = tid & 127;                  // V: col d
    const int vrb = (tid >> 7) * 8;             // V: 8 consecutive k (0/8/16/24)
    const float* Kbase = K + (size_t)kvh * HD + scc * 8;
    const float* Vbase = V + (size_t)kvh * HD + vd;

    float kr[8], vr[8];

    auto load_regs = [&](int kb) {
        const float* kp = Kbase + (size_t)(kb + sr) * KSTR;
        *(f32x4*)&kr[0] = *(const f32x4*)kp;
        *(f32x4*)&kr[4] = *(const f32x4*)(kp + 4);
        #pragma unroll
        for (int j = 0; j < 8; ++j)
            vr[j] = Vbase[(size_t)(kb + vrb + j) * KSTR];
    };

    auto store_tile = [&](int b) {
        u32x4 t;
        t[0] = cvt_pk_bf16(kr[0], kr[1]);
        t[1] = cvt_pk_bf16(kr[2], kr[3]);
        t[2] = cvt_pk_bf16(kr[4], kr[5]);
        t[3] = cvt_pk_bf16(kr[6], kr[7]);
        *(u32x4*)&Ks[b][sr * K_STRIDE + scc * 8] = t;
        t[0] = cvt_pk_bf16(vr[0], vr[1]);
        t[1] = cvt_pk_bf16(vr[2], vr[3]);
        t[2] = cvt_pk_bf16(vr[4], vr[5]);
        t[3] = cvt_pk_bf16(vr[6], vr[7]);
        *(u32x4*)&VTs[b][vd * VT_STRIDE + vrb] = t;
    };

    load_regs(kb_start);
    store_tile(0);
    int cur = 0;

    for (int kb = kb_start; kb < kv_end; kb += BK) {
        // one barrier per tile; vmcnt NOT drained (prefetch spans barrier)
        asm volatile("s_waitcnt lgkmcnt(0)\n\ts_barrier" ::: "memory");

        const bool has_next = (kb + BK) < kv_end;
        if (has_next) load_regs(kb + BK);

        const bool live = (kb <= qrow0 + 15) &&
                          (slope * (float)(qrow0 - kb - 31) < 45.0f);
        if (live) {
            const short* Kc = &Ks[cur][0];
            const short* Vc = &VTs[cur][0];

            // ---- S^T = K·Q^T : A = K rows (k), B = Q (col = q = l16) ----
            f32x4 sc0 = (f32x4){0.f,0.f,0.f,0.f};   // k = kb + 4*lq + i
            f32x4 sc1 = (f32x4){0.f,0.f,0.f,0.f};   // k = kb + 16 + 4*lq + i
            #pragma unroll
            for (int d0 = 0; d0 < 4; ++d0) {
                bf16x8 kf0 = *(const bf16x8*)&Kc[l16 * K_STRIDE + d0 * 32 + lq * 8];
                bf16x8 kf1 = *(const bf16x8*)&Kc[(16 + l16) * K_STRIDE + d0 * 32 + lq * 8];
                sc0 = __builtin_amdgcn_mfma_f32_16x16x32_bf16(kf0, qf[d0], sc0, 0, 0, 0);
                sc1 = __builtin_amdgcn_mfma_f32_16x16x32_bf16(kf1, qf[d0], sc1, 0, 0, 0);
            }

            // ---- bias + causal, all per-lane (q fixed = l16 col) ----
            const int kq0 = kb + 4 * lq - q;         // k - q at subtile A, i=0
            float s[8];
            #pragma unroll
            for (int i = 0; i < 4; ++i) {
                int d0i = kq0 + i, d1i = kq0 + 16 + i;
                float b0 = __builtin_fmaf(slope2, (float)d0i, sc0[i]);
                float b1 = __builtin_fmaf(slope2, (float)d1i, sc1[i]);
                s[i]     = (d0i > 0) ? -1e30f : b0;
                s[i + 4] = (d1i > 0) ? -1e30f : b1;
            }

            // ---- per-q max: 7 fmax + 2 shuffles ----
            float rm = fmaxf(fmaxf(fmaxf(s[0], s[1]), fmaxf(s[2], s[3])),
                             fmaxf(fmaxf(s[4], s[5]), fmaxf(s[6], s[7])));
            rm = fmaxf(rm, __shfl_xor(rm, 16));
            rm = fmaxf(rm, __shfl_xor(rm, 32));

            bool need = (rm > m_ + DTHR);
            if (__any(need)) {
                float mn    = need ? rm : m_;
                float alpha = exp2f(m_ - mn);        // 1.0 when !need
                m_ = mn;
                l_ *= alpha;
                #pragma unroll
                for (int t = 0; t < 8; ++t) {
                    acc[t][0] *= alpha; acc[t][1] *= alpha;
                    acc[t][2] *= alpha; acc[t][3] *= alpha;
                }
            }

            // ---- p = exp2(s - m); sum; pack ----
            float p[8];
            #pragma unroll
            for (int j = 0; j < 8; ++j) p[j] = exp2f(s[j] - m_);
            float ts = ((p[0] + p[1]) + (p[2] + p[3])) +
                       ((p[4] + p[5]) + (p[6] + p[7]));
            ts += __shfl_xor(ts, 16);
            ts += __shfl_xor(ts, 32);
            l_ += ts;

            u32x2 pa, pb;
            pa[0] = cvt_pk_bf16(p[0], p[1]); pa[1] = cvt_pk_bf16(p[2], p[3]);
            pb[0] = cvt_pk_bf16(p[4], p[5]); pb[1] = cvt_pk_bf16(p[6], p[7]);

            // ---- P[q][k] to LDS: two b64 writes, one b128 read ----
            short* PsW = &Ps[w][0];
            *(u32x2*)&PsW[l16 * P_STRIDE + 4 * lq]      = pa;  // k = 4lq..4lq+3
            *(u32x2*)&PsW[l16 * P_STRIDE + 16 + 4 * lq] = pb;  // k = 16+4lq..
            asm volatile("s_waitcnt lgkmcnt(0)" ::: "memory");
            bf16x8 pf = *(const bf16x8*)&PsW[l16 * P_STRIDE + lq * 8]; // k=8lq..+7

            // ---- O^T += V^T · P^T ----
            #pragma unroll
            for (int nt = 0; nt < 8; ++nt) {
                bf16x8 vf = *(const bf16x8*)&Vc[(nt * 16 + l16) * VT_STRIDE + lq * 8];
                acc[nt] = __builtin_amdgcn_mfma_f32_16x16x32_bf16(vf, pf, acc[nt], 0, 0, 0);
            }
        }

        if (has_next) store_tile(cur ^ 1);
        cur ^= 1;
    }

    // ---- epilogue: acc[t] = O[q][t*16 + 4lq .. +3], contiguous f32x4 ----
    {
        float rl = 1.0f / l_;
        float* op = O + (size_t)q * QSTR + h * HD + 4 * lq;
        #pragma unroll
        for (int nt = 0; nt < 8; ++nt) {
            f32x4 o = acc[nt];
            o[0] *= rl; o[1] *= rl; o[2] *= rl; o[3] *= rl;
            *(f32x4*)(op + nt * 16) = o;
        }
    }
}

extern "C" void kernel_launch(void* const* d_in, const int* in_sizes, int n_in,
                              void* d_out, int out_size, void* d_ws, size_t ws_size,
                              hipStream_t stream) {
    const float* Q  = (const float*)d_in[0];
    const float* K  = (const float*)d_in[1];
    const float* V  = (const float*)d_in[2];
    const float* SL = (const float*)d_in[3];
    float* O = (float*)d_out;

    dim3 grid(NQT * NHEADS);   // 512 blocks
    dim3 block(512);           // 8 waves
    attn_fwd<<<grid, block, 0, stream>>>(Q, K, V, SL, O);
}